// Round 1
// baseline (307.180 us; speedup 1.0000x reference)
//
#include <hip/hip_runtime.h>
#include <hip/hip_bf16.h>
#include <cstdint>
#include <math.h>

#define B_    2
#define S_    2048
#define DIM_  1536
#define H_    12
#define HD_   128
#define TRI_  4608   // 3*DIM
#define M_    4096   // B*S

typedef __attribute__((ext_vector_type(8))) __bf16 bf16x8;
typedef __attribute__((ext_vector_type(4))) __bf16 bf16x4;
typedef __attribute__((ext_vector_type(4))) float  floatx4;

typedef __attribute__((address_space(3))) uint8_t       lds_u8;
typedef const __attribute__((address_space(1))) uint8_t glob_u8;

// ---------------------------------------------------------------- cvt fp32->bf16
__global__ __launch_bounds__(256) void cvt_f32_bf16(const float* __restrict__ in,
                                                    __bf16* __restrict__ out, int n4) {
    int i = blockIdx.x * blockDim.x + threadIdx.x;
    if (i >= n4) return;
    float4 v = ((const float4*)in)[i];
    bf16x4 o;
    o.x = (__bf16)v.x; o.y = (__bf16)v.y; o.z = (__bf16)v.z; o.w = (__bf16)v.w;
    *(bf16x4*)(out + (size_t)i * 4) = o;
}

// ------------------------------------------------- transpose (R,C) f32 -> (C,R) bf16
__global__ __launch_bounds__(256) void transpose_cvt(const float* __restrict__ in,
                                                     __bf16* __restrict__ out,
                                                     int R, int C) {
    __shared__ float tile[32][33];
    int c0 = blockIdx.x * 32, r0 = blockIdx.y * 32;
    int tx = threadIdx.x, ty = threadIdx.y;   // block (32,8)
    #pragma unroll
    for (int i = 0; i < 32; i += 8)
        tile[ty + i][tx] = in[(size_t)(r0 + ty + i) * C + c0 + tx];
    __syncthreads();
    #pragma unroll
    for (int i = 0; i < 32; i += 8)
        out[(size_t)(c0 + ty + i) * R + r0 + tx] = (__bf16)tile[tx][ty + i];
}

// ------------------------------------------------------------------- bf16 GEMM-BT
// C[M,N] = A[M,K] * Bt[N,K]^T + bias ; 128x128 tile, BK=32, 4 waves of 64x64
template<bool OUT_BF16>
__global__ __launch_bounds__(256) void gemm_bt(const __bf16* __restrict__ A,
                                               const __bf16* __restrict__ Bt,
                                               const float*  __restrict__ bias,
                                               void* __restrict__ Cout,
                                               int Mdim, int Ndim, int Kdim) {
    __shared__ __align__(16) __bf16 sA[128 * 32];
    __shared__ __align__(16) __bf16 sB[128 * 32];

    const int ntiles = Ndim >> 7;
    const int tile_n = blockIdx.x % ntiles;
    const int tile_m = blockIdx.x / ntiles;
    const int m0 = tile_m << 7, n0 = tile_n << 7;

    const int tid  = threadIdx.x;
    const int lane = tid & 63;
    const int wave = tid >> 6;
    const int wm = (wave >> 1) * 64;   // wave row offset in tile
    const int wn = (wave & 1) * 64;    // wave col offset in tile

    floatx4 acc[4][4] = {};

    const int lr = lane >> 2;          // 0..15 : row within 16-row group
    const int lk = (lane & 3) * 8;     // 0,8,16,24 : k offset

    const int row  = lane & 15;
    const int quad = lane >> 4;

    for (int k0 = 0; k0 < Kdim; k0 += 32) {
        #pragma unroll
        for (int c = 0; c < 2; ++c) {
            int mrow = c * 64 + wave * 16;        // wave-uniform base row
            const __bf16* ga = A  + (size_t)(m0 + mrow + lr) * Kdim + k0 + lk;
            __builtin_amdgcn_global_load_lds((glob_u8*)ga, (lds_u8*)&sA[mrow * 32], 16, 0, 0);
            const __bf16* gb = Bt + (size_t)(n0 + mrow + lr) * Kdim + k0 + lk;
            __builtin_amdgcn_global_load_lds((glob_u8*)gb, (lds_u8*)&sB[mrow * 32], 16, 0, 0);
        }
        __syncthreads();

        bf16x8 af[4], bfr[4];
        #pragma unroll
        for (int i = 0; i < 4; ++i) {
            af[i]  = *(const bf16x8*)&sA[(wm + i * 16 + row) * 32 + quad * 8];
            bfr[i] = *(const bf16x8*)&sB[(wn + i * 16 + row) * 32 + quad * 8];
        }
        #pragma unroll
        for (int i = 0; i < 4; ++i)
            #pragma unroll
            for (int j = 0; j < 4; ++j)
                acc[i][j] = __builtin_amdgcn_mfma_f32_16x16x32_bf16(af[i], bfr[j], acc[i][j], 0, 0, 0);
        __syncthreads();
    }

    // epilogue: C/D layout col=lane&15, row=quad*4+r
    #pragma unroll
    for (int j = 0; j < 4; ++j) {
        int gc = n0 + wn + j * 16 + row;
        float bv = bias[gc];
        #pragma unroll
        for (int i = 0; i < 4; ++i) {
            #pragma unroll
            for (int r = 0; r < 4; ++r) {
                int gr = m0 + wm + i * 16 + quad * 4 + r;
                float v = acc[i][j][r] + bv;
                if (OUT_BF16)
                    ((__bf16*)Cout)[(size_t)gr * Ndim + gc] = (__bf16)v;
                else
                    ((float*)Cout)[(size_t)gr * Ndim + gc] = v;
            }
        }
    }
}

// ------------------------------------------------------------------ anchor attention
// one wave per (b,h,s); lane covers dims {2*lane, 2*lane+1}
__global__ __launch_bounds__(256) void anchor_attn(const __bf16* __restrict__ qkv,
                                                   const float* __restrict__ group_scale,
                                                   __bf16* __restrict__ attn_out) {
    const int S4 = S_ / 4;
    int blk = blockIdx.x;                 // B*H*S4
    int b   = blk / (H_ * S4);
    int rem = blk % (H_ * S4);
    int h   = rem / S4;
    int s4  = rem % S4;
    int wave = threadIdx.x >> 6, lane = threadIdx.x & 63;
    int s = s4 * 4 + wave;

    // group softmax -> log weights
    float g0 = group_scale[0], g1 = group_scale[1], g2 = group_scale[2];
    float gm = fmaxf(g0, fmaxf(g1, g2));
    float e0 = __expf(g0 - gm), e1 = __expf(g1 - gm), e2 = __expf(g2 - gm);
    float linv = __logf(e0 + e1 + e2);
    float lw0 = (g0 - gm) - linv, lw1 = (g1 - gm) - linv, lw2 = (g2 - gm) - linv;

    const int d0 = lane * 2;
    const size_t rowq = (size_t)(b * S_ + s) * TRI_ + h * HD_;
    float q0 = (float)qkv[rowq + d0], q1 = (float)qkv[rowq + d0 + 1];

    int idxs[12];
    const int offs[10] = {-3, -2, -1, 1, 2, 3, -10, -5, 5, 10};
    #pragma unroll
    for (int a = 0; a < 10; ++a) {
        int t = s + offs[a];
        idxs[a] = min(max(t, 0), S_ - 1);
    }
    idxs[10] = 0; idxs[11] = S_ - 1;

    const float scale = 0.08838834764831845f;  // 128^-0.5
    float sc[12];
    #pragma unroll
    for (int a = 0; a < 12; ++a) {
        const __bf16* kp = qkv + (size_t)(b * S_ + idxs[a]) * TRI_ + DIM_ + h * HD_ + d0;
        float part = q0 * (float)kp[0] + q1 * (float)kp[1];
        #pragma unroll
        for (int o = 32; o; o >>= 1) part += __shfl_xor(part, o);
        float lw = a < 6 ? lw0 : (a < 10 ? lw1 : lw2);
        sc[a] = part * scale + lw;
    }

    float mx = sc[0];
    #pragma unroll
    for (int a = 1; a < 12; ++a) mx = fmaxf(mx, sc[a]);
    float l = 0.f, p[12];
    #pragma unroll
    for (int a = 0; a < 12; ++a) { p[a] = __expf(sc[a] - mx); l += p[a]; }
    float inv = 1.0f / l;

    float o0 = 0.f, o1 = 0.f;
    #pragma unroll
    for (int a = 0; a < 12; ++a) {
        const __bf16* vp = qkv + (size_t)(b * S_ + idxs[a]) * TRI_ + 2 * DIM_ + h * HD_ + d0;
        o0 += p[a] * (float)vp[0];
        o1 += p[a] * (float)vp[1];
    }
    __bf16* op = attn_out + (size_t)(b * S_ + s) * DIM_ + h * HD_ + d0;
    op[0] = (__bf16)(o0 * inv);
    op[1] = (__bf16)(o1 * inv);
}

// ----------------------------------------------------------------------- launcher
extern "C" void kernel_launch(void* const* d_in, const int* in_sizes, int n_in,
                              void* d_out, int out_size, void* d_ws, size_t ws_size,
                              hipStream_t stream) {
    const float* x    = (const float*)d_in[0];   // (B,S,DIM)
    const float* Wqkv = (const float*)d_in[1];   // (DIM, 3*DIM)
    const float* bqkv = (const float*)d_in[2];   // (3*DIM)
    const float* Wout = (const float*)d_in[3];   // (DIM, DIM)
    const float* bout = (const float*)d_in[4];   // (DIM)
    const float* gsc  = (const float*)d_in[5];   // (3)
    float* out = (float*)d_out;

    char* ws = (char*)d_ws;
    __bf16* x_bf   = (__bf16*)(ws);                                        // 12.6 MB
    __bf16* WqkvT  = (__bf16*)(ws + 12582912);                             // 14.2 MB
    __bf16* WoutT  = (__bf16*)(ws + 12582912 + 14155776);                  // 4.7 MB
    __bf16* qkv    = (__bf16*)(ws + 12582912 + 14155776 + 4718592);        // 37.7 MB
    __bf16* attn   = (__bf16*)(ws + 12582912 + 14155776 + 4718592 + 37748736); // 12.6 MB

    // 1. convert x -> bf16
    {
        int n4 = (M_ * DIM_) / 4;
        cvt_f32_bf16<<<(n4 + 255) / 256, 256, 0, stream>>>(x, x_bf, n4);
    }
    // 2. transpose+convert weights
    transpose_cvt<<<dim3(TRI_ / 32, DIM_ / 32), dim3(32, 8), 0, stream>>>(Wqkv, WqkvT, DIM_, TRI_);
    transpose_cvt<<<dim3(DIM_ / 32, DIM_ / 32), dim3(32, 8), 0, stream>>>(Wout, WoutT, DIM_, DIM_);

    // 3. QKV GEMM: (4096,1536)x(1536,4608) -> bf16 qkv
    gemm_bt<true><<<(M_ / 128) * (TRI_ / 128), 256, 0, stream>>>(
        x_bf, WqkvT, bqkv, (void*)qkv, M_, TRI_, DIM_);

    // 4. anchor attention -> bf16 attn (B,S,DIM)
    anchor_attn<<<B_ * H_ * (S_ / 4), 256, 0, stream>>>(qkv, gsc, attn);

    // 5. out GEMM: (4096,1536)x(1536,1536) -> f32 out
    gemm_bt<false><<<(M_ / 128) * (DIM_ / 128), 256, 0, stream>>>(
        attn, WoutT, bout, (void*)out, M_, DIM_, DIM_);
}

// Round 2
// 288.845 us; speedup vs baseline: 1.0635x; 1.0635x over previous
//
#include <hip/hip_runtime.h>
#include <hip/hip_bf16.h>
#include <cstdint>
#include <math.h>

#define B_    2
#define S_    2048
#define DIM_  1536
#define H_    12
#define HD_   128
#define TRI_  4608   // 3*DIM
#define M_    4096   // B*S

typedef __attribute__((ext_vector_type(8))) __bf16 bf16x8;
typedef __attribute__((ext_vector_type(4))) __bf16 bf16x4;
typedef __attribute__((ext_vector_type(4))) float  floatx4;

typedef __attribute__((address_space(3))) uint8_t       lds_u8;
typedef const __attribute__((address_space(1))) uint8_t glob_u8;

// ---------------------------------------------------------------- cvt fp32->bf16
__global__ __launch_bounds__(256) void cvt_f32_bf16(const float* __restrict__ in,
                                                    __bf16* __restrict__ out, int n4) {
    int i = blockIdx.x * blockDim.x + threadIdx.x;
    if (i >= n4) return;
    float4 v = ((const float4*)in)[i];
    bf16x4 o;
    o.x = (__bf16)v.x; o.y = (__bf16)v.y; o.z = (__bf16)v.z; o.w = (__bf16)v.w;
    *(bf16x4*)(out + (size_t)i * 4) = o;
}

// ------------------------------------------------- transpose (R,C) f32 -> (C,R) bf16
__global__ __launch_bounds__(256) void transpose_cvt(const float* __restrict__ in,
                                                     __bf16* __restrict__ out,
                                                     int R, int C) {
    __shared__ float tile[32][33];
    int c0 = blockIdx.x * 32, r0 = blockIdx.y * 32;
    int tx = threadIdx.x, ty = threadIdx.y;   // block (32,8)
    #pragma unroll
    for (int i = 0; i < 32; i += 8)
        tile[ty + i][tx] = in[(size_t)(r0 + ty + i) * C + c0 + tx];
    __syncthreads();
    #pragma unroll
    for (int i = 0; i < 32; i += 8)
        out[(size_t)(c0 + ty + i) * R + r0 + tx] = (__bf16)tile[tx][ty + i];
}

// ------------------------------------------------------- bf16 GEMM-BT 128x128 BK=64
// C[M,N] = A[M,K]*Bt[N,K]^T + bias; 4 waves of 64x64, 16x16x32 MFMA
template<bool OUT_BF16>
__global__ __launch_bounds__(256) void gemm_bt(const __bf16* __restrict__ A,
                                               const __bf16* __restrict__ Bt,
                                               const float*  __restrict__ bias,
                                               void* __restrict__ Cout,
                                               int Mdim, int Ndim, int Kdim) {
    __shared__ __align__(16) __bf16 sA[128 * 64];   // 16 KB
    __shared__ __align__(16) __bf16 sB[128 * 64];   // 16 KB

    const int ntiles = Ndim >> 7;
    const int tile_n = blockIdx.x % ntiles;
    const int tile_m = blockIdx.x / ntiles;
    const int m0 = tile_m << 7, n0 = tile_n << 7;

    const int tid  = threadIdx.x;
    const int lane = tid & 63;
    const int wave = tid >> 6;
    const int wm = (wave >> 1) * 64;
    const int wn = (wave & 1) * 64;

    floatx4 acc[4][4] = {};

    const int lr8 = lane >> 3;          // 0..7 rows per staging instr
    const int lk8 = (lane & 7) * 8;     // k-elem offset 0..56

    const int row  = lane & 15;
    const int quad = lane >> 4;

    for (int k0 = 0; k0 < Kdim; k0 += 64) {
        #pragma unroll
        for (int c = 0; c < 4; ++c) {
            int r0 = (wave * 4 + c) * 8;   // wave-uniform
            const __bf16* ga = A  + (size_t)(m0 + r0 + lr8) * Kdim + k0 + lk8;
            __builtin_amdgcn_global_load_lds((glob_u8*)ga, (lds_u8*)&sA[r0 * 64], 16, 0, 0);
            const __bf16* gb = Bt + (size_t)(n0 + r0 + lr8) * Kdim + k0 + lk8;
            __builtin_amdgcn_global_load_lds((glob_u8*)gb, (lds_u8*)&sB[r0 * 64], 16, 0, 0);
        }
        __syncthreads();

        #pragma unroll
        for (int ks = 0; ks < 2; ++ks) {
            const int ko = ks * 32 + quad * 8;
            bf16x8 af[4], bfr[4];
            #pragma unroll
            for (int i = 0; i < 4; ++i) {
                af[i]  = *(const bf16x8*)&sA[(wm + i * 16 + row) * 64 + ko];
                bfr[i] = *(const bf16x8*)&sB[(wn + i * 16 + row) * 64 + ko];
            }
            #pragma unroll
            for (int i = 0; i < 4; ++i)
                #pragma unroll
                for (int j = 0; j < 4; ++j)
                    acc[i][j] = __builtin_amdgcn_mfma_f32_16x16x32_bf16(af[i], bfr[j], acc[i][j], 0, 0, 0);
        }
        __syncthreads();
    }

    #pragma unroll
    for (int j = 0; j < 4; ++j) {
        int gc = n0 + wn + j * 16 + row;
        float bv = bias[gc];
        #pragma unroll
        for (int i = 0; i < 4; ++i) {
            #pragma unroll
            for (int r = 0; r < 4; ++r) {
                int gr = m0 + wm + i * 16 + quad * 4 + r;
                float v = acc[i][j][r] + bv;
                if (OUT_BF16)
                    ((__bf16*)Cout)[(size_t)gr * Ndim + gc] = (__bf16)v;
                else
                    ((float*)Cout)[(size_t)gr * Ndim + gc] = v;
            }
        }
    }
}

// --------------------------------------------- bf16 GEMM-BT 128x256 BK=64 (QKV)
// 4 waves each 64x128 (4x8 of 16x16 frags)
__global__ __launch_bounds__(256, 2) void gemm_bt_big(const __bf16* __restrict__ A,
                                                      const __bf16* __restrict__ Bt,
                                                      const float*  __restrict__ bias,
                                                      __bf16* __restrict__ Cout,
                                                      int Mdim, int Ndim, int Kdim) {
    __shared__ __align__(16) __bf16 sA[128 * 64];   // 16 KB
    __shared__ __align__(16) __bf16 sB[256 * 64];   // 32 KB

    const int ntiles = Ndim >> 8;
    const int tile_n = blockIdx.x % ntiles;
    const int tile_m = blockIdx.x / ntiles;
    const int m0 = tile_m << 7, n0 = tile_n << 8;

    const int tid  = threadIdx.x;
    const int lane = tid & 63;
    const int wave = tid >> 6;
    const int wm = (wave >> 1) * 64;    // 0 or 64
    const int wn = (wave & 1) * 128;    // 0 or 128

    floatx4 acc[4][8] = {};

    const int lr8 = lane >> 3;
    const int lk8 = (lane & 7) * 8;
    const int row  = lane & 15;
    const int quad = lane >> 4;

    for (int k0 = 0; k0 < Kdim; k0 += 64) {
        #pragma unroll
        for (int c = 0; c < 4; ++c) {
            int r0 = (wave * 4 + c) * 8;
            const __bf16* ga = A + (size_t)(m0 + r0 + lr8) * Kdim + k0 + lk8;
            __builtin_amdgcn_global_load_lds((glob_u8*)ga, (lds_u8*)&sA[r0 * 64], 16, 0, 0);
        }
        #pragma unroll
        for (int c = 0; c < 8; ++c) {
            int r0 = (wave * 8 + c) * 8;
            const __bf16* gb = Bt + (size_t)(n0 + r0 + lr8) * Kdim + k0 + lk8;
            __builtin_amdgcn_global_load_lds((glob_u8*)gb, (lds_u8*)&sB[r0 * 64], 16, 0, 0);
        }
        __syncthreads();

        #pragma unroll
        for (int ks = 0; ks < 2; ++ks) {
            const int ko = ks * 32 + quad * 8;
            bf16x8 af[4], bfr[8];
            #pragma unroll
            for (int i = 0; i < 4; ++i)
                af[i] = *(const bf16x8*)&sA[(wm + i * 16 + row) * 64 + ko];
            #pragma unroll
            for (int j = 0; j < 8; ++j)
                bfr[j] = *(const bf16x8*)&sB[(wn + j * 16 + row) * 64 + ko];
            #pragma unroll
            for (int i = 0; i < 4; ++i)
                #pragma unroll
                for (int j = 0; j < 8; ++j)
                    acc[i][j] = __builtin_amdgcn_mfma_f32_16x16x32_bf16(af[i], bfr[j], acc[i][j], 0, 0, 0);
        }
        __syncthreads();
    }

    #pragma unroll
    for (int j = 0; j < 8; ++j) {
        int gc = n0 + wn + j * 16 + row;
        float bv = bias[gc];
        #pragma unroll
        for (int i = 0; i < 4; ++i) {
            #pragma unroll
            for (int r = 0; r < 4; ++r) {
                int gr = m0 + wm + i * 16 + quad * 4 + r;
                Cout[(size_t)gr * Ndim + gc] = (__bf16)(acc[i][j][r] + bv);
            }
        }
    }
}

// ------------------------------------------------------------------ anchor attention
// one block (192 thr) per (b,s); 16 lanes per head; lane group handles 8 dims
__global__ __launch_bounds__(192) void anchor_attn(const __bf16* __restrict__ qkv,
                                                   const float* __restrict__ group_scale,
                                                   __bf16* __restrict__ attn_out) {
    const int bs = blockIdx.x;
    const int b  = bs >> 11;          // S_=2048
    const int s  = bs & 2047;
    const int t  = threadIdx.x;
    const int h  = t >> 4;            // 0..11
    const int tt = t & 15;
    const int d0 = tt * 8;

    // group softmax -> log weights
    float g0 = group_scale[0], g1 = group_scale[1], g2 = group_scale[2];
    float gm = fmaxf(g0, fmaxf(g1, g2));
    float e0 = __expf(g0 - gm), e1 = __expf(g1 - gm), e2 = __expf(g2 - gm);
    float ls = __logf(e0 + e1 + e2);
    float lw0 = g0 - gm - ls, lw1 = g1 - gm - ls, lw2 = g2 - gm - ls;

    const size_t rowbase = (size_t)(b * S_ + s) * TRI_ + h * HD_ + d0;
    bf16x8 qv = *(const bf16x8*)(qkv + rowbase);
    float q[8];
    #pragma unroll
    for (int k = 0; k < 8; ++k) q[k] = (float)qv[k];

    int idxs[12];
    const int offs[10] = {-3, -2, -1, 1, 2, 3, -10, -5, 5, 10};
    #pragma unroll
    for (int a = 0; a < 10; ++a) {
        int tgt = s + offs[a];
        idxs[a] = min(max(tgt, 0), S_ - 1);
    }
    idxs[10] = 0; idxs[11] = S_ - 1;

    const float scale = 0.08838834764831845f;  // 128^-0.5
    float p[12];
    float mx = -1e30f;
    #pragma unroll
    for (int a = 0; a < 12; ++a) {
        const __bf16* kp = qkv + (size_t)(b * S_ + idxs[a]) * TRI_ + DIM_ + h * HD_ + d0;
        bf16x8 kv = *(const bf16x8*)kp;
        float d = 0.f;
        #pragma unroll
        for (int k = 0; k < 8; ++k) d += q[k] * (float)kv[k];
        d += __shfl_xor(d, 1); d += __shfl_xor(d, 2);
        d += __shfl_xor(d, 4); d += __shfl_xor(d, 8);
        float sc = d * scale + (a < 6 ? lw0 : (a < 10 ? lw1 : lw2));
        p[a] = sc;
        mx = fmaxf(mx, sc);
    }
    float l = 0.f;
    #pragma unroll
    for (int a = 0; a < 12; ++a) { p[a] = __expf(p[a] - mx); l += p[a]; }
    float inv = 1.0f / l;

    float o[8] = {};
    #pragma unroll
    for (int a = 0; a < 12; ++a) {
        const __bf16* vp = qkv + (size_t)(b * S_ + idxs[a]) * TRI_ + 2 * DIM_ + h * HD_ + d0;
        bf16x8 vv = *(const bf16x8*)vp;
        #pragma unroll
        for (int k = 0; k < 8; ++k) o[k] += p[a] * (float)vv[k];
    }
    bf16x8 ov;
    #pragma unroll
    for (int k = 0; k < 8; ++k) ov[k] = (__bf16)(o[k] * inv);
    *(bf16x8*)(attn_out + (size_t)(b * S_ + s) * DIM_ + h * HD_ + d0) = ov;
}

// ----------------------------------------------------------------------- launcher
extern "C" void kernel_launch(void* const* d_in, const int* in_sizes, int n_in,
                              void* d_out, int out_size, void* d_ws, size_t ws_size,
                              hipStream_t stream) {
    const float* x    = (const float*)d_in[0];
    const float* Wqkv = (const float*)d_in[1];
    const float* bqkv = (const float*)d_in[2];
    const float* Wout = (const float*)d_in[3];
    const float* bout = (const float*)d_in[4];
    const float* gsc  = (const float*)d_in[5];
    float* out = (float*)d_out;

    char* ws = (char*)d_ws;
    __bf16* x_bf   = (__bf16*)(ws);
    __bf16* WqkvT  = (__bf16*)(ws + 12582912);
    __bf16* WoutT  = (__bf16*)(ws + 12582912 + 14155776);
    __bf16* qkv    = (__bf16*)(ws + 12582912 + 14155776 + 4718592);
    __bf16* attn   = (__bf16*)(ws + 12582912 + 14155776 + 4718592 + 37748736);

    {
        int n4 = (M_ * DIM_) / 4;
        cvt_f32_bf16<<<(n4 + 255) / 256, 256, 0, stream>>>(x, x_bf, n4);
    }
    transpose_cvt<<<dim3(TRI_ / 32, DIM_ / 32), dim3(32, 8), 0, stream>>>(Wqkv, WqkvT, DIM_, TRI_);
    transpose_cvt<<<dim3(DIM_ / 32, DIM_ / 32), dim3(32, 8), 0, stream>>>(Wout, WoutT, DIM_, DIM_);

    // QKV GEMM: (4096,1536)x(1536,4608), 128x256 tiles -> 576 blocks
    gemm_bt_big<<<(M_ / 128) * (TRI_ / 256), 256, 0, stream>>>(
        x_bf, WqkvT, bqkv, qkv, M_, TRI_, DIM_);

    // anchor attention
    anchor_attn<<<B_ * S_, 192, 0, stream>>>(qkv, gsc, attn);

    // out GEMM: (4096,1536)x(1536,1536), 128x128 tiles -> 384 blocks
    gemm_bt<false><<<(M_ / 128) * (DIM_ / 128), 256, 0, stream>>>(
        attn, WoutT, bout, (void*)out, M_, DIM_, DIM_);
}

// Round 3
// 261.930 us; speedup vs baseline: 1.1728x; 1.1028x over previous
//
#include <hip/hip_runtime.h>
#include <hip/hip_bf16.h>
#include <cstdint>
#include <math.h>

#define B_    2
#define S_    2048
#define DIM_  1536
#define H_    12
#define HD_   128
#define TRI_  4608   // 3*DIM
#define M_    4096   // B*S

typedef __attribute__((ext_vector_type(8))) __bf16 bf16x8;
typedef __attribute__((ext_vector_type(4))) __bf16 bf16x4;
typedef __attribute__((ext_vector_type(4))) float  floatx4;

typedef __attribute__((address_space(3))) uint8_t       lds_u8;
typedef const __attribute__((address_space(1))) uint8_t glob_u8;

// ---------------------------------------------------------------- cvt fp32->bf16
__global__ __launch_bounds__(256) void cvt_f32_bf16(const float* __restrict__ in,
                                                    __bf16* __restrict__ out, int n4) {
    int i = blockIdx.x * blockDim.x + threadIdx.x;
    if (i >= n4) return;
    float4 v = ((const float4*)in)[i];
    bf16x4 o;
    o.x = (__bf16)v.x; o.y = (__bf16)v.y; o.z = (__bf16)v.z; o.w = (__bf16)v.w;
    *(bf16x4*)(out + (size_t)i * 4) = o;
}

// ------------------------------------------------- transpose (R,C) f32 -> (C,R) bf16
__global__ __launch_bounds__(256) void transpose_cvt(const float* __restrict__ in,
                                                     __bf16* __restrict__ out,
                                                     int R, int C) {
    __shared__ float tile[32][33];
    int c0 = blockIdx.x * 32, r0 = blockIdx.y * 32;
    int tx = threadIdx.x, ty = threadIdx.y;   // block (32,8)
    #pragma unroll
    for (int i = 0; i < 32; i += 8)
        tile[ty + i][tx] = in[(size_t)(r0 + ty + i) * C + c0 + tx];
    __syncthreads();
    #pragma unroll
    for (int i = 0; i < 32; i += 8)
        out[(size_t)(c0 + ty + i) * R + r0 + tx] = (__bf16)tile[tx][ty + i];
}

// ------------------------------------------------------- bf16 GEMM-BT 128x128 BK=64
// XOR-swizzled LDS: row r, chunk position p holds global k-chunk p^(r&7).
// Stage: lane loads global chunk (lane&7)^lr8; read: chunk (ks*4+quad)^(row&7).
template<bool OUT_BF16>
__global__ __launch_bounds__(256) void gemm_bt(const __bf16* __restrict__ A,
                                               const __bf16* __restrict__ Bt,
                                               const float*  __restrict__ bias,
                                               void* __restrict__ Cout,
                                               int Mdim, int Ndim, int Kdim) {
    __shared__ __align__(16) __bf16 sA[128 * 64];   // 16 KB
    __shared__ __align__(16) __bf16 sB[128 * 64];   // 16 KB

    const int ntiles = Ndim >> 7;
    const int tile_n = blockIdx.x % ntiles;
    const int tile_m = blockIdx.x / ntiles;
    const int m0 = tile_m << 7, n0 = tile_n << 7;

    const int tid  = threadIdx.x;
    const int lane = tid & 63;
    const int wave = tid >> 6;
    const int wm = (wave >> 1) * 64;
    const int wn = (wave & 1) * 64;

    floatx4 acc[4][4] = {};

    const int lr8 = lane >> 3;                       // 0..7 rows per staging instr
    const int swz = (((lane & 7) ^ lr8) * 8);        // swizzled k-elem offset

    const int row  = lane & 15;
    const int quad = lane >> 4;
    const int xr   = row & 7;

    for (int k0 = 0; k0 < Kdim; k0 += 64) {
        #pragma unroll
        for (int c = 0; c < 4; ++c) {
            int r0 = (wave * 4 + c) * 8;   // wave-uniform
            const __bf16* ga = A  + (size_t)(m0 + r0 + lr8) * Kdim + k0 + swz;
            __builtin_amdgcn_global_load_lds((glob_u8*)ga, (lds_u8*)&sA[r0 * 64], 16, 0, 0);
            const __bf16* gb = Bt + (size_t)(n0 + r0 + lr8) * Kdim + k0 + swz;
            __builtin_amdgcn_global_load_lds((glob_u8*)gb, (lds_u8*)&sB[r0 * 64], 16, 0, 0);
        }
        __syncthreads();

        #pragma unroll
        for (int ks = 0; ks < 2; ++ks) {
            const int ko = ((ks * 4 + quad) ^ xr) * 8;
            bf16x8 af[4], bfr[4];
            #pragma unroll
            for (int i = 0; i < 4; ++i) {
                af[i]  = *(const bf16x8*)&sA[(wm + i * 16 + row) * 64 + ko];
                bfr[i] = *(const bf16x8*)&sB[(wn + i * 16 + row) * 64 + ko];
            }
            #pragma unroll
            for (int i = 0; i < 4; ++i)
                #pragma unroll
                for (int j = 0; j < 4; ++j)
                    acc[i][j] = __builtin_amdgcn_mfma_f32_16x16x32_bf16(af[i], bfr[j], acc[i][j], 0, 0, 0);
        }
        __syncthreads();
    }

    #pragma unroll
    for (int j = 0; j < 4; ++j) {
        int gc = n0 + wn + j * 16 + row;
        float bv = bias[gc];
        #pragma unroll
        for (int i = 0; i < 4; ++i) {
            #pragma unroll
            for (int r = 0; r < 4; ++r) {
                int gr = m0 + wm + i * 16 + quad * 4 + r;
                float v = acc[i][j][r] + bv;
                if (OUT_BF16)
                    ((__bf16*)Cout)[(size_t)gr * Ndim + gc] = (__bf16)v;
                else
                    ((float*)Cout)[(size_t)gr * Ndim + gc] = v;
            }
        }
    }
}

// --------------------------------------------- bf16 GEMM-BT 128x256 BK=64 (QKV)
// 4 waves each 64x128 (4x8 of 16x16 frags); same XOR swizzle
__global__ __launch_bounds__(256, 2) void gemm_bt_big(const __bf16* __restrict__ A,
                                                      const __bf16* __restrict__ Bt,
                                                      const float*  __restrict__ bias,
                                                      __bf16* __restrict__ Cout,
                                                      int Mdim, int Ndim, int Kdim) {
    __shared__ __align__(16) __bf16 sA[128 * 64];   // 16 KB
    __shared__ __align__(16) __bf16 sB[256 * 64];   // 32 KB

    const int ntiles = Ndim >> 8;
    const int tile_n = blockIdx.x % ntiles;
    const int tile_m = blockIdx.x / ntiles;
    const int m0 = tile_m << 7, n0 = tile_n << 8;

    const int tid  = threadIdx.x;
    const int lane = tid & 63;
    const int wave = tid >> 6;
    const int wm = (wave >> 1) * 64;    // 0 or 64
    const int wn = (wave & 1) * 128;    // 0 or 128

    floatx4 acc[4][8] = {};

    const int lr8 = lane >> 3;
    const int swz = (((lane & 7) ^ lr8) * 8);
    const int row  = lane & 15;
    const int quad = lane >> 4;
    const int xr   = row & 7;

    for (int k0 = 0; k0 < Kdim; k0 += 64) {
        #pragma unroll
        for (int c = 0; c < 4; ++c) {
            int r0 = (wave * 4 + c) * 8;
            const __bf16* ga = A + (size_t)(m0 + r0 + lr8) * Kdim + k0 + swz;
            __builtin_amdgcn_global_load_lds((glob_u8*)ga, (lds_u8*)&sA[r0 * 64], 16, 0, 0);
        }
        #pragma unroll
        for (int c = 0; c < 8; ++c) {
            int r0 = (wave * 8 + c) * 8;
            const __bf16* gb = Bt + (size_t)(n0 + r0 + lr8) * Kdim + k0 + swz;
            __builtin_amdgcn_global_load_lds((glob_u8*)gb, (lds_u8*)&sB[r0 * 64], 16, 0, 0);
        }
        __syncthreads();

        #pragma unroll
        for (int ks = 0; ks < 2; ++ks) {
            const int ko = ((ks * 4 + quad) ^ xr) * 8;
            bf16x8 af[4], bfr[8];
            #pragma unroll
            for (int i = 0; i < 4; ++i)
                af[i] = *(const bf16x8*)&sA[(wm + i * 16 + row) * 64 + ko];
            #pragma unroll
            for (int j = 0; j < 8; ++j)
                bfr[j] = *(const bf16x8*)&sB[(wn + j * 16 + row) * 64 + ko];
            #pragma unroll
            for (int i = 0; i < 4; ++i)
                #pragma unroll
                for (int j = 0; j < 8; ++j)
                    acc[i][j] = __builtin_amdgcn_mfma_f32_16x16x32_bf16(af[i], bfr[j], acc[i][j], 0, 0, 0);
        }
        __syncthreads();
    }

    #pragma unroll
    for (int j = 0; j < 8; ++j) {
        int gc = n0 + wn + j * 16 + row;
        float bv = bias[gc];
        #pragma unroll
        for (int i = 0; i < 4; ++i) {
            #pragma unroll
            for (int r = 0; r < 4; ++r) {
                int gr = m0 + wm + i * 16 + quad * 4 + r;
                Cout[(size_t)gr * Ndim + gc] = (__bf16)(acc[i][j][r] + bv);
            }
        }
    }
}

// ------------------------------------------------------------------ anchor attention
// one block (192 thr) per (b,s); 16 lanes per head; lane group handles 8 dims
__global__ __launch_bounds__(192) void anchor_attn(const __bf16* __restrict__ qkv,
                                                   const float* __restrict__ group_scale,
                                                   __bf16* __restrict__ attn_out) {
    const int bs = blockIdx.x;
    const int b  = bs >> 11;          // S_=2048
    const int s  = bs & 2047;
    const int t  = threadIdx.x;
    const int h  = t >> 4;            // 0..11
    const int tt = t & 15;
    const int d0 = tt * 8;

    // group softmax -> log weights
    float g0 = group_scale[0], g1 = group_scale[1], g2 = group_scale[2];
    float gm = fmaxf(g0, fmaxf(g1, g2));
    float e0 = __expf(g0 - gm), e1 = __expf(g1 - gm), e2 = __expf(g2 - gm);
    float ls = __logf(e0 + e1 + e2);
    float lw0 = g0 - gm - ls, lw1 = g1 - gm - ls, lw2 = g2 - gm - ls;

    const size_t rowbase = (size_t)(b * S_ + s) * TRI_ + h * HD_ + d0;
    bf16x8 qv = *(const bf16x8*)(qkv + rowbase);
    float q[8];
    #pragma unroll
    for (int k = 0; k < 8; ++k) q[k] = (float)qv[k];

    int idxs[12];
    const int offs[10] = {-3, -2, -1, 1, 2, 3, -10, -5, 5, 10};
    #pragma unroll
    for (int a = 0; a < 10; ++a) {
        int tgt = s + offs[a];
        idxs[a] = min(max(tgt, 0), S_ - 1);
    }
    idxs[10] = 0; idxs[11] = S_ - 1;

    const float scale = 0.08838834764831845f;  // 128^-0.5
    float p[12];
    float mx = -1e30f;
    #pragma unroll
    for (int a = 0; a < 12; ++a) {
        const __bf16* kp = qkv + (size_t)(b * S_ + idxs[a]) * TRI_ + DIM_ + h * HD_ + d0;
        bf16x8 kv = *(const bf16x8*)kp;
        float d = 0.f;
        #pragma unroll
        for (int k = 0; k < 8; ++k) d += q[k] * (float)kv[k];
        d += __shfl_xor(d, 1); d += __shfl_xor(d, 2);
        d += __shfl_xor(d, 4); d += __shfl_xor(d, 8);
        float sc = d * scale + (a < 6 ? lw0 : (a < 10 ? lw1 : lw2));
        p[a] = sc;
        mx = fmaxf(mx, sc);
    }
    float l = 0.f;
    #pragma unroll
    for (int a = 0; a < 12; ++a) { p[a] = __expf(p[a] - mx); l += p[a]; }
    float inv = 1.0f / l;

    float o[8] = {};
    #pragma unroll
    for (int a = 0; a < 12; ++a) {
        const __bf16* vp = qkv + (size_t)(b * S_ + idxs[a]) * TRI_ + 2 * DIM_ + h * HD_ + d0;
        bf16x8 vv = *(const bf16x8*)vp;
        #pragma unroll
        for (int k = 0; k < 8; ++k) o[k] += p[a] * (float)vv[k];
    }
    bf16x8 ov;
    #pragma unroll
    for (int k = 0; k < 8; ++k) ov[k] = (__bf16)(o[k] * inv);
    *(bf16x8*)(attn_out + (size_t)(b * S_ + s) * DIM_ + h * HD_ + d0) = ov;
}

// ----------------------------------------------------------------------- launcher
extern "C" void kernel_launch(void* const* d_in, const int* in_sizes, int n_in,
                              void* d_out, int out_size, void* d_ws, size_t ws_size,
                              hipStream_t stream) {
    const float* x    = (const float*)d_in[0];
    const float* Wqkv = (const float*)d_in[1];
    const float* bqkv = (const float*)d_in[2];
    const float* Wout = (const float*)d_in[3];
    const float* bout = (const float*)d_in[4];
    const float* gsc  = (const float*)d_in[5];
    float* out = (float*)d_out;

    char* ws = (char*)d_ws;
    __bf16* x_bf   = (__bf16*)(ws);
    __bf16* WqkvT  = (__bf16*)(ws + 12582912);
    __bf16* WoutT  = (__bf16*)(ws + 12582912 + 14155776);
    __bf16* qkv    = (__bf16*)(ws + 12582912 + 14155776 + 4718592);
    __bf16* attn   = (__bf16*)(ws + 12582912 + 14155776 + 4718592 + 37748736);

    {
        int n4 = (M_ * DIM_) / 4;
        cvt_f32_bf16<<<(n4 + 255) / 256, 256, 0, stream>>>(x, x_bf, n4);
    }
    transpose_cvt<<<dim3(TRI_ / 32, DIM_ / 32), dim3(32, 8), 0, stream>>>(Wqkv, WqkvT, DIM_, TRI_);
    transpose_cvt<<<dim3(DIM_ / 32, DIM_ / 32), dim3(32, 8), 0, stream>>>(Wout, WoutT, DIM_, DIM_);

    // QKV GEMM: (4096,1536)x(1536,4608), 128x256 tiles -> 576 blocks
    gemm_bt_big<<<(M_ / 128) * (TRI_ / 256), 256, 0, stream>>>(
        x_bf, WqkvT, bqkv, qkv, M_, TRI_, DIM_);

    // anchor attention
    anchor_attn<<<B_ * S_, 192, 0, stream>>>(qkv, gsc, attn);

    // out GEMM: (4096,1536)x(1536,1536), 128x128 tiles -> 384 blocks
    gemm_bt<false><<<(M_ / 128) * (DIM_ / 128), 256, 0, stream>>>(
        attn, WoutT, bout, (void*)out, M_, DIM_, DIM_);
}